// Round 4
// baseline (201.930 us; speedup 1.0000x reference)
//
#include <hip/hip_runtime.h>
#include <hip/hip_bf16.h>
#include <stdint.h>

#define NODE_DIM 128
#define N_NODES  100000
#define N_EDGES  600000
#define NOUT     256          // 2*NODE_DIM: [A | B] per node row

typedef __bf16 bf16x8 __attribute__((ext_vector_type(8)));
typedef float  f32x4  __attribute__((ext_vector_type(4)));

static __device__ inline unsigned pack2_bf16(float a, float b) {
    unsigned short ua = __builtin_bit_cast(unsigned short, (__bf16)a);
    unsigned short ub = __builtin_bit_cast(unsigned short, (__bf16)b);
    return (unsigned)ua | ((unsigned)ub << 16);
}

// ---------------------------------------------------------------------------
// Kernel 0: transpose+cast W1 [256][128] f32 (k-major) into Wt [256][128] bf16
// laid out Wt[n'][k]: n'<128 -> W1[k][n'], n'>=128 -> W1[128+k][n'-128].
// ---------------------------------------------------------------------------
__global__ void wprep_kernel(const float* __restrict__ W1, __bf16* __restrict__ Wt) {
    int i = blockIdx.x * 256 + threadIdx.x;        // 0..32767
    if (i >= NOUT * NODE_DIM) return;
    int kp = i >> 7;                               // 0..255 (pair-k)
    int n  = i & 127;
    float v = W1[i];                               // coalesced read
    int np = (kp < NODE_DIM) ? n  : (n + NODE_DIM);
    int k  = (kp < NODE_DIM) ? kp : (kp - NODE_DIM);
    Wt[np * NODE_DIM + k] = (__bf16)v;             // scattered 2B write (64 KB total)
}

// ---------------------------------------------------------------------------
// Kernel 1: AB[m][n'] = sum_k x[m][k] * W'[k][n']  (+ b1 folded into n'<128)
// M=100000, N=256, K=128.
// Round-4 shape: block = 512 thr (8 waves); wave w owns n-span [32w, 32w+32);
// MT=32 rows/block.  Per-wave state: B 32 VGPR + acc 16 + staging 16 -> ~80
// unified regs -> 6 waves/SIMD (was 3 at 144).  Occupancy is the lever: the
// r3 kernel was stall-bound (all pipes <10%) at 1.44 TB/s effective.
// Epilogue via LDS for fully-coalesced dwordx4 stores (r2 lesson: scattered
// 2B stores double WRITE_SIZE).
// ---------------------------------------------------------------------------
#define MT   32
#define ELD  264   // LDS row stride (el): 132 words % 32 = 4 -> write groups
                   // land <=2-way per bank (free, m136); measured 0 conflicts

__global__ __launch_bounds__(512)
void gemm_pre_kernel(const float* __restrict__ x, const __bf16* __restrict__ Wt,
                     const float* __restrict__ b1, __bf16* __restrict__ AB) {
    __shared__ __align__(16) __bf16 Ls[MT][ELD];   // 16896 B

    const int t    = threadIdx.x;
    const int wave = t >> 6;      // 0..7
    const int lane = t & 63;
    const int lm   = lane & 15;   // m (A) / n (B) within a 16-tile
    const int q    = lane >> 4;   // quad: k group of 8 (inputs) / m group of 4 (C/D)
    const int m0   = blockIdx.x * MT;   // grid 3125 covers 100000 exactly
    const int n0   = wave * 32;

    // ---- B fragments: n = n0 + nt*16 + lm, k = ks*32 + q*8 + j ----
    bf16x8 bfr[2][4];
#pragma unroll
    for (int nt = 0; nt < 2; ++nt) {
        const int n = n0 + nt * 16 + lm;
#pragma unroll
        for (int ks = 0; ks < 4; ++ks)
            bfr[nt][ks] = __builtin_bit_cast(bf16x8,
                *(const uint4*)(Wt + (size_t)n * NODE_DIM + ks * 32 + q * 8));
    }

    f32x4 acc[2][2];   // [mt][nt]
#pragma unroll
    for (int i = 0; i < 2; ++i)
#pragma unroll
        for (int j = 0; j < 2; ++j)
            acc[i][j] = (f32x4){0.f, 0.f, 0.f, 0.f};

#pragma unroll
    for (int mt = 0; mt < 2; ++mt) {
        const int m = m0 + mt * 16 + lm;
        const float* xr = x + (size_t)m * NODE_DIM + q * 8;
        float4 xa[4][2];                             // 8 independent 16B loads in flight
#pragma unroll
        for (int ks = 0; ks < 4; ++ks) {
            xa[ks][0] = *(const float4*)(xr + ks * 32);
            xa[ks][1] = *(const float4*)(xr + ks * 32 + 4);
        }
#pragma unroll
        for (int ks = 0; ks < 4; ++ks) {
            uint4 p;
            p.x = pack2_bf16(xa[ks][0].x, xa[ks][0].y);
            p.y = pack2_bf16(xa[ks][0].z, xa[ks][0].w);
            p.z = pack2_bf16(xa[ks][1].x, xa[ks][1].y);
            p.w = pack2_bf16(xa[ks][1].z, xa[ks][1].w);
            bf16x8 af = __builtin_bit_cast(bf16x8, p);
#pragma unroll
            for (int nt = 0; nt < 2; ++nt)
                acc[mt][nt] = __builtin_amdgcn_mfma_f32_16x16x32_bf16(
                    af, bfr[nt][ks], acc[mt][nt], 0, 0, 0);
        }
    }

    // ---- epilogue: fold b1 (n<128), bf16 into LDS tile ----
    // C/D layout (verified): col = lane&15, row-in-16-tile = q*4 + r
#pragma unroll
    for (int nt = 0; nt < 2; ++nt) {
        const int n = n0 + nt * 16 + lm;
        const float bias = (n < NODE_DIM) ? b1[n] : 0.f;
#pragma unroll
        for (int mt = 0; mt < 2; ++mt) {
#pragma unroll
            for (int r = 0; r < 4; ++r)
                Ls[mt * 16 + q * 4 + r][n] = (__bf16)(acc[mt][nt][r] + bias);
        }
    }
    __syncthreads();

    // ---- coalesced store: 512 thr x 16B cover 16 full 512B rows/iter ----
    const int c8 = (t & 31) * 8;                      // element col, 32 thr/row
#pragma unroll
    for (int i = 0; i < 2; ++i) {
        const int row = i * 16 + (t >> 5);
        *(uint4*)(AB + (size_t)(m0 + row) * NOUT + c8) = *(const uint4*)(&Ls[row][c8]);
    }
}

// ---------------------------------------------------------------------------
// Kernel 2: per edge e: h = relu(AB[src][0:128] + AB[dst][128:256]) (b1 already
// folded); out[e] = sigmoid(h . W2 + b2).  16 lanes per edge, 8 ch per lane.
// 2-edge unroll: 4 gathers in flight per lane for more memory-level parallelism.
// ---------------------------------------------------------------------------
__global__ __launch_bounds__(256)
void edge_score_kernel(const __bf16* __restrict__ AB, const int* __restrict__ idx,
                       const float* __restrict__ W2, const float* __restrict__ b2,
                       float* __restrict__ out) {
    const int t      = threadIdx.x;
    const int sub    = t & 15;                           // channel-slice id
    const int g0     = (blockIdx.x * 256 + t) >> 4;      // first edge for this group
    const int stride = (gridDim.x * 256) >> 4;

    float w[8];
#pragma unroll
    for (int j = 0; j < 8; ++j) w[j] = W2[sub * 8 + j];
    const float bias2 = b2[0];

    for (int e = g0; e < N_EDGES; e += 2 * stride) {
        const int e1   = e + stride;
        const bool h1  = e1 < N_EDGES;
        const int s0 = idx[e];
        const int d0 = idx[N_EDGES + e];
        const int s1 = h1 ? idx[e1] : s0;
        const int d1 = h1 ? idx[N_EDGES + e1] : d0;

        const uint4 av0 = *(const uint4*)(AB + (size_t)s0 * NOUT + sub * 8);
        const uint4 bv0 = *(const uint4*)(AB + (size_t)d0 * NOUT + NODE_DIM + sub * 8);
        const uint4 av1 = *(const uint4*)(AB + (size_t)s1 * NOUT + sub * 8);
        const uint4 bv1 = *(const uint4*)(AB + (size_t)d1 * NOUT + NODE_DIM + sub * 8);

        const unsigned* au0 = (const unsigned*)&av0;
        const unsigned* bu0 = (const unsigned*)&bv0;
        const unsigned* au1 = (const unsigned*)&av1;
        const unsigned* bu1 = (const unsigned*)&bv1;
        float p0 = 0.f, p1 = 0.f;
#pragma unroll
        for (int j = 0; j < 4; ++j) {
            float a0 = __builtin_bit_cast(float, au0[j] << 16);
            float a1 = __builtin_bit_cast(float, au0[j] & 0xffff0000u);
            float c0 = __builtin_bit_cast(float, bu0[j] << 16);
            float c1 = __builtin_bit_cast(float, bu0[j] & 0xffff0000u);
            p0 = fmaf(fmaxf(a0 + c0, 0.f), w[2 * j],     p0);
            p0 = fmaf(fmaxf(a1 + c1, 0.f), w[2 * j + 1], p0);
            float e0 = __builtin_bit_cast(float, au1[j] << 16);
            float e1f= __builtin_bit_cast(float, au1[j] & 0xffff0000u);
            float f0 = __builtin_bit_cast(float, bu1[j] << 16);
            float f1 = __builtin_bit_cast(float, bu1[j] & 0xffff0000u);
            p1 = fmaf(fmaxf(e0 + f0, 0.f), w[2 * j],     p1);
            p1 = fmaf(fmaxf(e1f+ f1, 0.f), w[2 * j + 1], p1);
        }
        p0 += __shfl_xor(p0, 1);  p1 += __shfl_xor(p1, 1);
        p0 += __shfl_xor(p0, 2);  p1 += __shfl_xor(p1, 2);
        p0 += __shfl_xor(p0, 4);  p1 += __shfl_xor(p1, 4);
        p0 += __shfl_xor(p0, 8);  p1 += __shfl_xor(p1, 8);
        if (sub == 0) {
            out[e] = 1.f / (1.f + __expf(-(p0 + bias2)));
            if (h1) out[e1] = 1.f / (1.f + __expf(-(p1 + bias2)));
        }
    }
}

// ---------------------------------------------------------------------------
// Fallback (only if workspace is too small): one block per edge, direct MLP.
// ---------------------------------------------------------------------------
__global__ __launch_bounds__(128)
void naive_edge_kernel(const float* __restrict__ x, const int* __restrict__ idx,
                       const float* __restrict__ W1, const float* __restrict__ b1,
                       const float* __restrict__ W2, const float* __restrict__ b2,
                       float* __restrict__ out) {
    __shared__ float pair[2 * NODE_DIM];
    __shared__ float red[2];
    int e = blockIdx.x;
    int t = threadIdx.x;                  // 0..127
    int s = idx[e], d = idx[N_EDGES + e];
    pair[t]            = x[(size_t)s * NODE_DIM + t];
    pair[NODE_DIM + t] = x[(size_t)d * NODE_DIM + t];
    __syncthreads();
    float acc = b1[t];
    for (int k = 0; k < 2 * NODE_DIM; ++k)
        acc = fmaf(pair[k], W1[k * NODE_DIM + t], acc);
    float c = fmaxf(acc, 0.f) * W2[t];
#pragma unroll
    for (int m = 1; m < 64; m <<= 1) c += __shfl_xor(c, m);
    if ((t & 63) == 0) red[t >> 6] = c;
    __syncthreads();
    if (t == 0) out[e] = 1.f / (1.f + __expf(-(red[0] + red[1] + b2[0])));
}

// ---------------------------------------------------------------------------
extern "C" void kernel_launch(void* const* d_in, const int* in_sizes, int n_in,
                              void* d_out, int out_size, void* d_ws, size_t ws_size,
                              hipStream_t stream) {
    const float* x   = (const float*)d_in[0];
    const int*   idx = (const int*)d_in[1];     // [2][N_EDGES] int32
    const float* W1  = (const float*)d_in[2];   // [256][128]
    const float* b1  = (const float*)d_in[3];   // [128]
    const float* W2  = (const float*)d_in[4];   // [128]
    const float* b2  = (const float*)d_in[5];   // [1]
    float* out = (float*)d_out;                 // [N_EDGES]

    const size_t ab_bytes = (size_t)N_NODES * NOUT * sizeof(__bf16);   // 51.2 MB
    const size_t wt_bytes = (size_t)NOUT * NODE_DIM * sizeof(__bf16);  // 64 KB

    if (ws_size >= ab_bytes + wt_bytes) {
        __bf16* AB = (__bf16*)d_ws;
        __bf16* Wt = (__bf16*)((char*)d_ws + ab_bytes);
        hipLaunchKernelGGL(wprep_kernel, dim3(128), dim3(256), 0, stream, W1, Wt);
        hipLaunchKernelGGL(gemm_pre_kernel, dim3(N_NODES / MT), dim3(512),
                           0, stream, x, Wt, b1, AB);
        hipLaunchKernelGGL(edge_score_kernel, dim3(2048), dim3(256), 0, stream,
                           AB, idx, W2, b2, out);
    } else {
        hipLaunchKernelGGL(naive_edge_kernel, dim3(N_EDGES), dim3(128), 0, stream,
                           x, idx, W1, b1, W2, b2, out);
    }
}

// Round 5
// 173.537 us; speedup vs baseline: 1.1636x; 1.1636x over previous
//
#include <hip/hip_runtime.h>
#include <hip/hip_bf16.h>
#include <stdint.h>

#define NODE_DIM 128
#define N_NODES  100000
#define N_EDGES  600000
#define NOUT     256          // 2*NODE_DIM: [A | B] per node row

typedef __bf16 bf16x8 __attribute__((ext_vector_type(8)));
typedef float  f32x4  __attribute__((ext_vector_type(4)));

static __device__ inline unsigned pack2_bf16(float a, float b) {
    unsigned short ua = __builtin_bit_cast(unsigned short, (__bf16)a);
    unsigned short ub = __builtin_bit_cast(unsigned short, (__bf16)b);
    return (unsigned)ua | ((unsigned)ub << 16);
}

// ---------------------------------------------------------------------------
// Kernel 0: transpose+cast W1 [256][128] f32 (k-major) into Wt [256][128] bf16
// laid out Wt[n'][k]: n'<128 -> W1[k][n'], n'>=128 -> W1[128+k][n'-128].
// ---------------------------------------------------------------------------
__global__ void wprep_kernel(const float* __restrict__ W1, __bf16* __restrict__ Wt) {
    int i = blockIdx.x * 256 + threadIdx.x;        // 0..32767
    if (i >= NOUT * NODE_DIM) return;
    int kp = i >> 7;                               // 0..255 (pair-k)
    int n  = i & 127;
    float v = W1[i];                               // coalesced read
    int np = (kp < NODE_DIM) ? n  : (n + NODE_DIM);
    int k  = (kp < NODE_DIM) ? kp : (kp - NODE_DIM);
    Wt[np * NODE_DIM + k] = (__bf16)v;             // scattered 2B write (64 KB total)
}

// ---------------------------------------------------------------------------
// Kernel 1: AB[m][n'] = sum_k x[m][k] * W'[k][n']  (+ b1 folded into n'<128)
// M=100000, N=256, K=128.
// Round-5 shape (r3 geometry + max bytes-in-flight):
//   - block 256 (4 waves), MT=64 rows, wave w owns n-span [64w, 64w+64)
//   - ALL 32 staging float4 loads hoisted before any pack/MFMA (32 KB/wave
//     in flight across one latency window).  r4 lesson: occupancy doesn't
//     matter here, bytes-in-flight does; r4's 32-VGPR allocation serialized
//     the loads and regressed.
//   - __launch_bounds__(256, 1): let the allocator keep ~300 VGPRs live.
//   - Epilogue via LDS -> fully-coalesced dwordx4 stores (r2 lesson).
// ---------------------------------------------------------------------------
#define MT   64
#define ELD  264   // LDS row stride (el): 132 words % 32 = 4 -> <=2-way (free,
                   // m136); measured 0 conflicts in r3/r4

__global__ __launch_bounds__(256, 1)
void gemm_pre_kernel(const float* __restrict__ x, const __bf16* __restrict__ Wt,
                     const float* __restrict__ b1, __bf16* __restrict__ AB) {
    __shared__ __align__(16) __bf16 Ls[MT][ELD];   // 33792 B

    const int t    = threadIdx.x;
    const int wave = t >> 6;      // 0..3
    const int lane = t & 63;
    const int lm   = lane & 15;   // m (A) / n (B) within a 16-tile
    const int q    = lane >> 4;   // quad: k group of 8 (inputs) / m group of 4 (C/D)
    const int m0   = blockIdx.x * MT;
    const int n0   = wave * 64;

    // ---- B fragments: n = n0 + nt*16 + lm, k = ks*32 + q*8 + j ----
    bf16x8 bfr[4][4];
#pragma unroll
    for (int nt = 0; nt < 4; ++nt) {
        const int n = n0 + nt * 16 + lm;
#pragma unroll
        for (int ks = 0; ks < 4; ++ks)
            bfr[nt][ks] = __builtin_bit_cast(bf16x8,
                *(const uint4*)(Wt + (size_t)n * NODE_DIM + ks * 32 + q * 8));
    }

    // ---- ALL staging loads issued before any consumption ----
    float4 xa[4][4][2];                  // [mt][ks][half] : 128 VGPRs
#pragma unroll
    for (int mt = 0; mt < 4; ++mt) {
        int m = m0 + mt * 16 + lm;
        if (m > N_NODES - 1) m = N_NODES - 1;    // clamp; stores are guarded
        const float* xr = x + (size_t)m * NODE_DIM + q * 8;
#pragma unroll
        for (int ks = 0; ks < 4; ++ks) {
            xa[mt][ks][0] = *(const float4*)(xr + ks * 32);
            xa[mt][ks][1] = *(const float4*)(xr + ks * 32 + 4);
        }
    }

    f32x4 acc[4][4];   // [mt][nt]
#pragma unroll
    for (int i = 0; i < 4; ++i)
#pragma unroll
        for (int j = 0; j < 4; ++j)
            acc[i][j] = (f32x4){0.f, 0.f, 0.f, 0.f};

    // ---- consume in load order (compiler can use graduated vmcnt) ----
#pragma unroll
    for (int mt = 0; mt < 4; ++mt) {
#pragma unroll
        for (int ks = 0; ks < 4; ++ks) {
            uint4 p;
            p.x = pack2_bf16(xa[mt][ks][0].x, xa[mt][ks][0].y);
            p.y = pack2_bf16(xa[mt][ks][0].z, xa[mt][ks][0].w);
            p.z = pack2_bf16(xa[mt][ks][1].x, xa[mt][ks][1].y);
            p.w = pack2_bf16(xa[mt][ks][1].z, xa[mt][ks][1].w);
            bf16x8 af = __builtin_bit_cast(bf16x8, p);
#pragma unroll
            for (int nt = 0; nt < 4; ++nt)
                acc[mt][nt] = __builtin_amdgcn_mfma_f32_16x16x32_bf16(
                    af, bfr[nt][ks], acc[mt][nt], 0, 0, 0);
        }
    }

    // ---- epilogue: fold b1 (n<128), bf16 into LDS tile ----
    // C/D layout (verified): col = lane&15, row-in-16-tile = q*4 + r
#pragma unroll
    for (int nt = 0; nt < 4; ++nt) {
        const int n = n0 + nt * 16 + lm;
        const float bias = (n < NODE_DIM) ? b1[n] : 0.f;
#pragma unroll
        for (int mt = 0; mt < 4; ++mt) {
#pragma unroll
            for (int r = 0; r < 4; ++r)
                Ls[mt * 16 + q * 4 + r][n] = (__bf16)(acc[mt][nt][r] + bias);
        }
    }
    __syncthreads();

    // ---- coalesced store: 256 threads x 16B cover 8 full 512B rows/iter ----
    const int c8 = (t & 31) * 8;                      // element col, 32 thr/row
#pragma unroll
    for (int i = 0; i < 8; ++i) {
        const int row = i * 8 + (t >> 5);
        const int m = m0 + row;
        if (m < N_NODES)
            *(uint4*)(AB + (size_t)m * NOUT + c8) = *(const uint4*)(&Ls[row][c8]);
    }
}

// ---------------------------------------------------------------------------
// Kernel 2: per edge e: h = relu(AB[src][0:128] + AB[dst][128:256]) (b1 already
// folded); out[e] = sigmoid(h . W2 + b2).  16 lanes per edge, 8 ch per lane.
// 2-edge unroll: 4 gathers in flight per lane.
// ---------------------------------------------------------------------------
__global__ __launch_bounds__(256)
void edge_score_kernel(const __bf16* __restrict__ AB, const int* __restrict__ idx,
                       const float* __restrict__ W2, const float* __restrict__ b2,
                       float* __restrict__ out) {
    const int t      = threadIdx.x;
    const int sub    = t & 15;                           // channel-slice id
    const int g0     = (blockIdx.x * 256 + t) >> 4;      // first edge for this group
    const int stride = (gridDim.x * 256) >> 4;

    float w[8];
#pragma unroll
    for (int j = 0; j < 8; ++j) w[j] = W2[sub * 8 + j];
    const float bias2 = b2[0];

    for (int e = g0; e < N_EDGES; e += 2 * stride) {
        const int e1   = e + stride;
        const bool h1  = e1 < N_EDGES;
        const int s0 = idx[e];
        const int d0 = idx[N_EDGES + e];
        const int s1 = h1 ? idx[e1] : s0;
        const int d1 = h1 ? idx[N_EDGES + e1] : d0;

        const uint4 av0 = *(const uint4*)(AB + (size_t)s0 * NOUT + sub * 8);
        const uint4 bv0 = *(const uint4*)(AB + (size_t)d0 * NOUT + NODE_DIM + sub * 8);
        const uint4 av1 = *(const uint4*)(AB + (size_t)s1 * NOUT + sub * 8);
        const uint4 bv1 = *(const uint4*)(AB + (size_t)d1 * NOUT + NODE_DIM + sub * 8);

        const unsigned* au0 = (const unsigned*)&av0;
        const unsigned* bu0 = (const unsigned*)&bv0;
        const unsigned* au1 = (const unsigned*)&av1;
        const unsigned* bu1 = (const unsigned*)&bv1;
        float p0 = 0.f, p1 = 0.f;
#pragma unroll
        for (int j = 0; j < 4; ++j) {
            float a0 = __builtin_bit_cast(float, au0[j] << 16);
            float a1 = __builtin_bit_cast(float, au0[j] & 0xffff0000u);
            float c0 = __builtin_bit_cast(float, bu0[j] << 16);
            float c1 = __builtin_bit_cast(float, bu0[j] & 0xffff0000u);
            p0 = fmaf(fmaxf(a0 + c0, 0.f), w[2 * j],     p0);
            p0 = fmaf(fmaxf(a1 + c1, 0.f), w[2 * j + 1], p0);
            float e0 = __builtin_bit_cast(float, au1[j] << 16);
            float e1f= __builtin_bit_cast(float, au1[j] & 0xffff0000u);
            float f0 = __builtin_bit_cast(float, bu1[j] << 16);
            float f1 = __builtin_bit_cast(float, bu1[j] & 0xffff0000u);
            p1 = fmaf(fmaxf(e0 + f0, 0.f), w[2 * j],     p1);
            p1 = fmaf(fmaxf(e1f+ f1, 0.f), w[2 * j + 1], p1);
        }
        p0 += __shfl_xor(p0, 1);  p1 += __shfl_xor(p1, 1);
        p0 += __shfl_xor(p0, 2);  p1 += __shfl_xor(p1, 2);
        p0 += __shfl_xor(p0, 4);  p1 += __shfl_xor(p1, 4);
        p0 += __shfl_xor(p0, 8);  p1 += __shfl_xor(p1, 8);
        if (sub == 0) {
            out[e] = 1.f / (1.f + __expf(-(p0 + bias2)));
            if (h1) out[e1] = 1.f / (1.f + __expf(-(p1 + bias2)));
        }
    }
}

// ---------------------------------------------------------------------------
// Fallback (only if workspace is too small): one block per edge, direct MLP.
// ---------------------------------------------------------------------------
__global__ __launch_bounds__(128)
void naive_edge_kernel(const float* __restrict__ x, const int* __restrict__ idx,
                       const float* __restrict__ W1, const float* __restrict__ b1,
                       const float* __restrict__ W2, const float* __restrict__ b2,
                       float* __restrict__ out) {
    __shared__ float pair[2 * NODE_DIM];
    __shared__ float red[2];
    int e = blockIdx.x;
    int t = threadIdx.x;                  // 0..127
    int s = idx[e], d = idx[N_EDGES + e];
    pair[t]            = x[(size_t)s * NODE_DIM + t];
    pair[NODE_DIM + t] = x[(size_t)d * NODE_DIM + t];
    __syncthreads();
    float acc = b1[t];
    for (int k = 0; k < 2 * NODE_DIM; ++k)
        acc = fmaf(pair[k], W1[k * NODE_DIM + t], acc);
    float c = fmaxf(acc, 0.f) * W2[t];
#pragma unroll
    for (int m = 1; m < 64; m <<= 1) c += __shfl_xor(c, m);
    if ((t & 63) == 0) red[t >> 6] = c;
    __syncthreads();
    if (t == 0) out[e] = 1.f / (1.f + __expf(-(red[0] + red[1] + b2[0])));
}

// ---------------------------------------------------------------------------
extern "C" void kernel_launch(void* const* d_in, const int* in_sizes, int n_in,
                              void* d_out, int out_size, void* d_ws, size_t ws_size,
                              hipStream_t stream) {
    const float* x   = (const float*)d_in[0];
    const int*   idx = (const int*)d_in[1];     // [2][N_EDGES] int32
    const float* W1  = (const float*)d_in[2];   // [256][128]
    const float* b1  = (const float*)d_in[3];   // [128]
    const float* W2  = (const float*)d_in[4];   // [128]
    const float* b2  = (const float*)d_in[5];   // [1]
    float* out = (float*)d_out;                 // [N_EDGES]

    const size_t ab_bytes = (size_t)N_NODES * NOUT * sizeof(__bf16);   // 51.2 MB
    const size_t wt_bytes = (size_t)NOUT * NODE_DIM * sizeof(__bf16);  // 64 KB

    if (ws_size >= ab_bytes + wt_bytes) {
        __bf16* AB = (__bf16*)d_ws;
        __bf16* Wt = (__bf16*)((char*)d_ws + ab_bytes);
        hipLaunchKernelGGL(wprep_kernel, dim3(128), dim3(256), 0, stream, W1, Wt);
        hipLaunchKernelGGL(gemm_pre_kernel, dim3((N_NODES + MT - 1) / MT), dim3(256),
                           0, stream, x, Wt, b1, AB);
        hipLaunchKernelGGL(edge_score_kernel, dim3(2048), dim3(256), 0, stream,
                           AB, idx, W2, b2, out);
    } else {
        hipLaunchKernelGGL(naive_edge_kernel, dim3(N_EDGES), dim3(128), 0, stream,
                           x, idx, W1, b1, W2, b2, out);
    }
}